// Round 3
// baseline (408.366 us; speedup 1.0000x reference)
//
#include <hip/hip_runtime.h>

// ---------------- problem constants ----------------
#define DIM    192
#define HEADS  6
#define HD     32
#define NTOK   64
#define NWIN   512
#define NBLK   2048
#define TPB    384          // 6 waves, one head per wave
#define XPITCH 200          // xin row pitch (ushorts): 192 + 8 pad
#define MPITCH 65           // madd row pitch (floats)

typedef short  bf16x4 __attribute__((ext_vector_type(4)));
typedef short  bf16x8 __attribute__((ext_vector_type(8)));
typedef float  f32x4  __attribute__((ext_vector_type(4)));

// NOTE: guard must be device-pass only — on the HOST pass of HIP's dual
// compilation __has_builtin(amdgcn builtins) is false and #error fires.
#if defined(__HIP_DEVICE_COMPILE__)
#if !__has_builtin(__builtin_amdgcn_mfma_f32_16x16x32_bf16)
#error "missing __builtin_amdgcn_mfma_f32_16x16x32_bf16"
#endif
#if !__has_builtin(__builtin_amdgcn_mfma_f32_16x16x16bf16_1k)
#error "missing __builtin_amdgcn_mfma_f32_16x16x16bf16_1k"
#endif
#endif

static __device__ __forceinline__ unsigned short f2bf(float f){
  unsigned u = __builtin_bit_cast(unsigned, f);
  u += 0x7FFFu + ((u >> 16) & 1u);          // round-to-nearest-even
  return (unsigned short)(u >> 16);
}

static __device__ __forceinline__ f32x4 mfma32(bf16x8 a, bf16x8 b, f32x4 c){
  return __builtin_amdgcn_mfma_f32_16x16x32_bf16(a, b, c, 0, 0, 0);
}
static __device__ __forceinline__ f32x4 mfma16(bf16x4 a, bf16x4 b, f32x4 c){
  return __builtin_amdgcn_mfma_f32_16x16x16bf16_1k(a, b, c, 0, 0, 0);
}

// 8-wide bf16 fragment from a weight row (fp32 global -> bf16 regs).
// Serves as A-frag (rows at lane&15) for transposed projections and as
// B-frag (cols at lane&15) for normal-orientation GEMMs: W[c][k] either way.
static __device__ __forceinline__ bf16x8 load_wfrag(const float* __restrict__ W, int row, int k0){
  const float4 a = *(const float4*)(W + row*DIM + k0);
  const float4 b = *(const float4*)(W + row*DIM + k0 + 4);
  bf16x8 r;
  r[0]=(short)f2bf(a.x); r[1]=(short)f2bf(a.y); r[2]=(short)f2bf(a.z); r[3]=(short)f2bf(a.w);
  r[4]=(short)f2bf(b.x); r[5]=(short)f2bf(b.y); r[6]=(short)f2bf(b.z); r[7]=(short)f2bf(b.w);
  return r;
}

// cooperative fp32 window (64x192) -> bf16 LDS tile [64][XPITCH]
static __device__ __forceinline__ void stage_xin(unsigned short* xin, const float* __restrict__ src, int t){
  #pragma unroll
  for (int j = 0; j < 8; ++j){
    const int i4  = t + j*TPB;              // 3072 float4 total
    const float4 f = ((const float4*)src)[i4];
    const int row = i4 / 48;                // 48 float4 per row
    const int col = (i4 - row*48) * 4;
    uint2 u;
    u.x = (unsigned)f2bf(f.x) | ((unsigned)f2bf(f.y) << 16);
    u.y = (unsigned)f2bf(f.z) | ((unsigned)f2bf(f.w) << 16);
    *(uint2*)(xin + row*XPITCH + col) = u;
  }
}

// ---- attn_mask dtype probe: 0 = int32 {0,1}, 1 = packed bytes, 2 = float32 ----
// int32 mode: all words in {0,1}. byte mode: random 0/1 bytes -> many words with
// bits above bit0 set. float mode: words in {0, 0x3F800000}. Misclassification
// probability over 4096 random bool words is ~2^-3072.
__global__ void detect_amask_kernel(const unsigned int* __restrict__ am, int* __restrict__ mode){
  __shared__ int sawFloat, sawByte;
  if (threadIdx.x == 0){ sawFloat = 0; sawByte = 0; }
  __syncthreads();
  const uint4 ld = ((const uint4*)am)[threadIdx.x];   // 256 threads * 16B = 4KB
  unsigned w[4] = {ld.x, ld.y, ld.z, ld.w};
  int f = 0, bm = 0;
  #pragma unroll
  for (int i = 0; i < 4; ++i){
    if (w[i] == 0x3F800000u) f = 1;
    else if (w[i] & ~1u)     bm = 1;
  }
  if (f)  atomicOr(&sawFloat, 1);
  if (bm) atomicOr(&sawByte, 1);
  __syncthreads();
  if (threadIdx.x == 0) *mode = sawFloat ? 2 : (sawByte ? 1 : 0);
}

// bias_pre[h][m][n] = rpb_table[rel_idx[n][m]*HEADS + h]   (98.3 KB in d_ws)
__global__ void bias_pre_kernel(const float* __restrict__ rpb, const int* __restrict__ rel_idx,
                                float* __restrict__ bias_pre){
  const int e = blockIdx.x*256 + threadIdx.x;
  if (e >= HEADS*NTOK*NTOK) return;
  const int rest = e & 4095, m = rest >> 6, n = rest & 63;
  bias_pre[e] = rpb[rel_idx[n*NTOK + m]*HEADS + (e >> 12)];
}

// Fragment layout facts used (gfx950, m89-verified family):
//   mfma 16x16x32: A[row=l&15][k=8g+i], B[k=8g+i][col=l&15], C: col=l&15,row=4g+r
//   mfma 16x16x16: A[row=l&15][k=4g+r], B[k=4g+r][col=l&15], C: col=l&15,row=4g+r
// Chain: Q/K proj computed TRANSPOSED (A=W) -> C regs are exactly the
// 16x16x16 A/B frags of S^T = Kh*Qh^T; softmaxed S^T regs are exactly the
// B-frag of out^T = Vh^T * P^T whose A-frag is the V-proj C regs. No LDS
// transposes anywhere in the attention core.
__global__ __launch_bounds__(TPB, 2) void swin_kernel(
  const float* __restrict__ q, const float* __restrict__ kin, const float* __restrict__ vin,
  const float* __restrict__ mask, const void* __restrict__ amask,
  const float* __restrict__ Wq, const float* __restrict__ bq,
  const float* __restrict__ Wk, const float* __restrict__ bk,
  const float* __restrict__ Wv, const float* __restrict__ bv,
  const float* __restrict__ Wp, const float* __restrict__ bp,
  const float* __restrict__ bias_pre, const int* __restrict__ mflag,
  float* __restrict__ out)
{
  __shared__ unsigned short xin[NTOK * XPITCH];  // 25.6 KB, reused q->k->v->xout
  __shared__ float madd[NTOK * MPITCH];          // 16.6 KB, [m][n] = mask + (-1e9 if attn_mask)

  const int b    = blockIdx.x;
  const int t    = threadIdx.x;
  const int h    = t >> 6;          // wave == head
  const int lane = t & 63;
  const int l15  = lane & 15;
  const int g    = lane >> 4;
  const int c0   = h * HD;
  const size_t base = (size_t)b * (NTOK * DIM);
  const float scale = 0.17677669529663687f;   // 1/sqrt(32)
  const f32x4 fz = {0.f, 0.f, 0.f, 0.f};

  // ---------- phase 0: additive mask tile + stage q ----------
  {
    const int mode = mflag[0];
    const float* mrow = mask + (size_t)(b & (NWIN-1)) * (NTOK*NTOK);
    const size_t abase = (size_t)b * (NTOK*NTOK);
    for (int i = t; i < NTOK*NTOK; i += TPB){
      const int n = i >> 6, m = i & 63;
      bool msk;
      if (mode == 0)      msk = ((const int*)amask)[abase + i] != 0;
      else if (mode == 1) msk = ((const unsigned char*)amask)[abase + i] != 0;
      else                msk = ((const float*)amask)[abase + i] != 0.0f;
      madd[m*MPITCH + n] = mrow[i] + (msk ? -1e9f : 0.0f);
    }
    stage_xin(xin, q + base, t);
  }
  __syncthreads();

  bf16x4 Qf[4][2], Kf[4][2], Vf[2][4];

  // ---------- Q projection (transposed): Qh^T[c][n], c in [c0,c0+32) ----------
  {
    f32x4 acc[2][4];
    #pragma unroll
    for (int a0=0;a0<2;++a0){
      #pragma unroll
      for (int a1=0;a1<4;++a1) acc[a0][a1] = fz;
    }
    #pragma unroll
    for (int kt = 0; kt < 6; ++kt){
      const int k0 = kt*32 + g*8;
      const bf16x8 w0 = load_wfrag(Wq, c0 + l15, k0);
      const bf16x8 w1 = load_wfrag(Wq, c0 + 16 + l15, k0);
      #pragma unroll
      for (int nt = 0; nt < 4; ++nt){
        const bf16x8 xf = *(const bf16x8*)(xin + (nt*16 + l15)*XPITCH + k0);
        acc[0][nt] = mfma32(w0, xf, acc[0][nt]);
        acc[1][nt] = mfma32(w1, xf, acc[1][nt]);
      }
    }
    #pragma unroll
    for (int dt = 0; dt < 2; ++dt){
      const float4 bb = *(const float4*)(bq + c0 + dt*16 + g*4);
      #pragma unroll
      for (int nt = 0; nt < 4; ++nt){
        bf16x4 f;
        f[0]=(short)f2bf((acc[dt][nt][0]+bb.x)*scale);
        f[1]=(short)f2bf((acc[dt][nt][1]+bb.y)*scale);
        f[2]=(short)f2bf((acc[dt][nt][2]+bb.z)*scale);
        f[3]=(short)f2bf((acc[dt][nt][3]+bb.w)*scale);
        Qf[nt][dt] = f;
      }
    }
  }
  __syncthreads();
  stage_xin(xin, kin + base, t);
  __syncthreads();

  // ---------- K projection (transposed): Kh^T[c][m] ----------
  {
    f32x4 acc[2][4];
    #pragma unroll
    for (int a0=0;a0<2;++a0){
      #pragma unroll
      for (int a1=0;a1<4;++a1) acc[a0][a1] = fz;
    }
    #pragma unroll
    for (int kt = 0; kt < 6; ++kt){
      const int k0 = kt*32 + g*8;
      const bf16x8 w0 = load_wfrag(Wk, c0 + l15, k0);
      const bf16x8 w1 = load_wfrag(Wk, c0 + 16 + l15, k0);
      #pragma unroll
      for (int mt = 0; mt < 4; ++mt){
        const bf16x8 xf = *(const bf16x8*)(xin + (mt*16 + l15)*XPITCH + k0);
        acc[0][mt] = mfma32(w0, xf, acc[0][mt]);
        acc[1][mt] = mfma32(w1, xf, acc[1][mt]);
      }
    }
    #pragma unroll
    for (int dt = 0; dt < 2; ++dt){
      const float4 bb = *(const float4*)(bk + c0 + dt*16 + g*4);
      #pragma unroll
      for (int mt = 0; mt < 4; ++mt){
        bf16x4 f;
        f[0]=(short)f2bf(acc[dt][mt][0]+bb.x);
        f[1]=(short)f2bf(acc[dt][mt][1]+bb.y);
        f[2]=(short)f2bf(acc[dt][mt][2]+bb.z);
        f[3]=(short)f2bf(acc[dt][mt][3]+bb.w);
        Kf[mt][dt] = f;
      }
    }
  }
  __syncthreads();
  stage_xin(xin, vin + base, t);
  __syncthreads();

  // ---------- V projection (normal): Vh[m][c] -> C regs ARE Vh^T A-frags ----------
  {
    f32x4 acc[4][2];
    #pragma unroll
    for (int a0=0;a0<4;++a0){
      #pragma unroll
      for (int a1=0;a1<2;++a1) acc[a0][a1] = fz;
    }
    #pragma unroll
    for (int kt = 0; kt < 6; ++kt){
      const int k0 = kt*32 + g*8;
      const bf16x8 w0 = load_wfrag(Wv, c0 + l15, k0);      // B-frag: Wv[c][k]
      const bf16x8 w1 = load_wfrag(Wv, c0 + 16 + l15, k0);
      #pragma unroll
      for (int mt = 0; mt < 4; ++mt){
        const bf16x8 xf = *(const bf16x8*)(xin + (mt*16 + l15)*XPITCH + k0);
        acc[mt][0] = mfma32(xf, w0, acc[mt][0]);
        acc[mt][1] = mfma32(xf, w1, acc[mt][1]);
      }
    }
    const float bv0 = bv[c0 + l15];
    const float bv1 = bv[c0 + 16 + l15];
    #pragma unroll
    for (int mt = 0; mt < 4; ++mt){
      bf16x4 f0, f1;
      f0[0]=(short)f2bf(acc[mt][0][0]+bv0); f0[1]=(short)f2bf(acc[mt][0][1]+bv0);
      f0[2]=(short)f2bf(acc[mt][0][2]+bv0); f0[3]=(short)f2bf(acc[mt][0][3]+bv0);
      f1[0]=(short)f2bf(acc[mt][1][0]+bv1); f1[1]=(short)f2bf(acc[mt][1][1]+bv1);
      f1[2]=(short)f2bf(acc[mt][1][2]+bv1); f1[3]=(short)f2bf(acc[mt][1][3]+bv1);
      Vf[0][mt] = f0;  // A[row=d=l15][k=m=4g+r], d-tile 0, m-step mt
      Vf[1][mt] = f1;  // d-tile 1
    }
  }
  __syncthreads();   // xin now free -> becomes xout

  // ---------- S^T = Kh * Qh^T : C[col=n=l15+16nt][row=m=4g+r+16mt] ----------
  f32x4 s[4][4];
  #pragma unroll
  for (int mt = 0; mt < 4; ++mt){
    #pragma unroll
    for (int nt = 0; nt < 4; ++nt){
      f32x4 a = mfma16(Kf[mt][0], Qf[nt][0], fz);
      s[mt][nt] = mfma16(Kf[mt][1], Qf[nt][1], a);
    }
  }

  // ---------- bias/mask add + softmax over m (in-lane 16 + shfl_xor 16,32) ----------
  const float* bh = bias_pre + h * (NTOK*NTOK);
  bf16x4 Pf[4][4];
  #pragma unroll
  for (int nt = 0; nt < 4; ++nt){
    const int n = nt*16 + l15;
    float mx = -3.0e38f;
    #pragma unroll
    for (int mt = 0; mt < 4; ++mt){
      #pragma unroll
      for (int r = 0; r < 4; ++r){
        const int m = mt*16 + g*4 + r;
        const float val = s[mt][nt][r] + madd[m*MPITCH + n] + bh[m*64 + n];
        s[mt][nt][r] = val;
        mx = fmaxf(mx, val);
      }
    }
    mx = fmaxf(mx, __shfl_xor(mx, 16, 64));
    mx = fmaxf(mx, __shfl_xor(mx, 32, 64));
    float sum = 0.f;
    #pragma unroll
    for (int mt = 0; mt < 4; ++mt){
      #pragma unroll
      for (int r = 0; r < 4; ++r){
        const float e = __expf(s[mt][nt][r] - mx);
        s[mt][nt][r] = e;
        sum += e;
      }
    }
    sum += __shfl_xor(sum, 16, 64);
    sum += __shfl_xor(sum, 32, 64);
    const float inv = 1.0f / sum;
    #pragma unroll
    for (int ms = 0; ms < 4; ++ms){
      bf16x4 f;
      f[0]=(short)f2bf(s[ms][nt][0]*inv); f[1]=(short)f2bf(s[ms][nt][1]*inv);
      f[2]=(short)f2bf(s[ms][nt][2]*inv); f[3]=(short)f2bf(s[ms][nt][3]*inv);
      Pf[nt][ms] = f;   // B-frag: P^T[m=4g+r+16ms][n=l15+16nt]
    }
  }

  // ---------- out^T = Vh^T * P^T : C[col=n][row=d=4g+r+16dt] ----------
  f32x4 o[2][4];
  #pragma unroll
  for (int a0=0;a0<2;++a0){
    #pragma unroll
    for (int a1=0;a1<4;++a1) o[a0][a1] = fz;
  }
  #pragma unroll
  for (int ms = 0; ms < 4; ++ms){
    #pragma unroll
    for (int dt = 0; dt < 2; ++dt){
      #pragma unroll
      for (int nt = 0; nt < 4; ++nt){
        o[dt][nt] = mfma16(Vf[dt][ms], Pf[nt][ms], o[dt][nt]);
      }
    }
  }

  // ---------- write attention output into xout (=xin buffer), bf16 ----------
  #pragma unroll
  for (int dt = 0; dt < 2; ++dt){
    #pragma unroll
    for (int nt = 0; nt < 4; ++nt){
      const int n   = nt*16 + l15;
      const int col = c0 + dt*16 + g*4;       // 4 consecutive d per lane
      uint2 u;
      u.x = (unsigned)f2bf(o[dt][nt][0]) | ((unsigned)f2bf(o[dt][nt][1]) << 16);
      u.y = (unsigned)f2bf(o[dt][nt][2]) | ((unsigned)f2bf(o[dt][nt][3]) << 16);
      *(uint2*)(xin + n*XPITCH + col) = u;
    }
  }
  __syncthreads();

  // ---------- final projection: out[n][c] = xout @ Wp^T + bp ----------
  {
    f32x4 acc[4][2];
    #pragma unroll
    for (int a0=0;a0<4;++a0){
      #pragma unroll
      for (int a1=0;a1<2;++a1) acc[a0][a1] = fz;
    }
    #pragma unroll
    for (int kt = 0; kt < 6; ++kt){
      const int k0 = kt*32 + g*8;
      const bf16x8 w0 = load_wfrag(Wp, c0 + l15, k0);
      const bf16x8 w1 = load_wfrag(Wp, c0 + 16 + l15, k0);
      #pragma unroll
      for (int nt = 0; nt < 4; ++nt){
        const bf16x8 xf = *(const bf16x8*)(xin + (nt*16 + l15)*XPITCH + k0);
        acc[nt][0] = mfma32(xf, w0, acc[nt][0]);
        acc[nt][1] = mfma32(xf, w1, acc[nt][1]);
      }
    }
    const float bp0 = bp[c0 + l15];
    const float bp1 = bp[c0 + 16 + l15];
    #pragma unroll
    for (int nt = 0; nt < 4; ++nt){
      #pragma unroll
      for (int ctl = 0; ctl < 2; ++ctl){
        const int c = c0 + ctl*16 + l15;
        const float badd = ctl ? bp1 : bp0;
        #pragma unroll
        for (int r = 0; r < 4; ++r){
          const int n = nt*16 + g*4 + r;
          out[base + (size_t)(n*DIM + c)] = acc[nt][ctl][r] + badd;
        }
      }
    }
  }
}

extern "C" void kernel_launch(void* const* d_in, const int* in_sizes, int n_in,
                              void* d_out, int out_size, void* d_ws, size_t ws_size,
                              hipStream_t stream){
  const float* q     = (const float*)d_in[0];
  const float* k     = (const float*)d_in[1];
  const float* v     = (const float*)d_in[2];
  const float* mask  = (const float*)d_in[3];
  const void*  amask = d_in[4];               // dtype resolved by device probe
  const float* Wq    = (const float*)d_in[5];
  const float* bq    = (const float*)d_in[6];
  const float* Wk    = (const float*)d_in[7];
  const float* bk    = (const float*)d_in[8];
  const float* Wv    = (const float*)d_in[9];
  const float* bv    = (const float*)d_in[10];
  const float* Wp    = (const float*)d_in[11];
  const float* bp    = (const float*)d_in[12];
  const float* rpb   = (const float*)d_in[13];
  const int*   ridx  = (const int*)d_in[14];
  float* out = (float*)d_out;
  float* bias_pre = (float*)d_ws;                    // 6*64*64 floats = 98304 B
  int*   mflag    = (int*)((char*)d_ws + 98304);     // 4 B mode flag

  detect_amask_kernel<<<1, 256, 0, stream>>>((const unsigned int*)amask, mflag);
  bias_pre_kernel<<<96, 256, 0, stream>>>(rpb, ridx, bias_pre);
  swin_kernel<<<NBLK, TPB, 0, stream>>>(q, k, v, mask, amask,
                                        Wq, bq, Wk, bk, Wv, bv, Wp, bp,
                                        bias_pre, mflag, out);
}

// Round 4
// 378.008 us; speedup vs baseline: 1.0803x; 1.0803x over previous
//
#include <hip/hip_runtime.h>

// ---------------- problem constants ----------------
#define DIM    192
#define HEADS  6
#define HD     32
#define NTOK   64
#define NWIN   512
#define NBLK   2048
#define TPB    384          // 6 waves, one head per wave
#define XPITCH 200          // x tile row pitch (ushorts): 192 + 8 pad
#define MPITCH 65           // madd row pitch (floats)
#define WMAT   (DIM*DIM)    // 36864 elements per weight matrix

typedef short  bf16x4 __attribute__((ext_vector_type(4)));
typedef short  bf16x8 __attribute__((ext_vector_type(8)));
typedef float  f32x4  __attribute__((ext_vector_type(4)));

// NOTE: guard must be device-pass only — on the HOST pass of HIP's dual
// compilation __has_builtin(amdgcn builtins) is false and #error fires.
#if defined(__HIP_DEVICE_COMPILE__)
#if !__has_builtin(__builtin_amdgcn_mfma_f32_16x16x32_bf16)
#error "missing __builtin_amdgcn_mfma_f32_16x16x32_bf16"
#endif
#if !__has_builtin(__builtin_amdgcn_mfma_f32_16x16x16bf16_1k)
#error "missing __builtin_amdgcn_mfma_f32_16x16x16bf16_1k"
#endif
#endif

static __device__ __forceinline__ unsigned short f2bf(float f){
  unsigned u = __builtin_bit_cast(unsigned, f);
  u += 0x7FFFu + ((u >> 16) & 1u);          // round-to-nearest-even
  return (unsigned short)(u >> 16);
}

static __device__ __forceinline__ f32x4 mfma32(bf16x8 a, bf16x8 b, f32x4 c){
  return __builtin_amdgcn_mfma_f32_16x16x32_bf16(a, b, c, 0, 0, 0);
}
static __device__ __forceinline__ f32x4 mfma16(bf16x4 a, bf16x4 b, f32x4 c){
  return __builtin_amdgcn_mfma_f32_16x16x16bf16_1k(a, b, c, 0, 0, 0);
}

// bf16 weight fragment: ONE 16B load (weights pre-converted in d_ws).
static __device__ __forceinline__ bf16x8 wfrag(const unsigned short* __restrict__ W, int row, int k0){
  return *(const bf16x8*)(W + row*DIM + k0);
}

// convert a staged float4 pair into packed bf16 (uint2) for LDS
static __device__ __forceinline__ uint2 pack_bf(const float4 f){
  uint2 u;
  u.x = (unsigned)f2bf(f.x) | ((unsigned)f2bf(f.y) << 16);
  u.y = (unsigned)f2bf(f.z) | ((unsigned)f2bf(f.w) << 16);
  return u;
}

// cooperative fp32 window (64x192) -> bf16 LDS tile [64][XPITCH]
static __device__ __forceinline__ void stage_xin(unsigned short* xt, const float* __restrict__ src, int t){
  #pragma unroll
  for (int j = 0; j < 8; ++j){
    const int i4  = t + j*TPB;              // 3072 float4 total
    const float4 f = ((const float4*)src)[i4];
    const int row = i4 / 48;                // 48 float4 per row
    const int col = (i4 - row*48) * 4;
    *(uint2*)(xt + row*XPITCH + col) = pack_bf(f);
  }
}

// ---- attn_mask dtype probe: 0 = int32 {0,1}, 1 = packed bytes, 2 = float32 ----
__global__ void detect_amask_kernel(const unsigned int* __restrict__ am, int* __restrict__ mode){
  __shared__ int sawFloat, sawByte;
  if (threadIdx.x == 0){ sawFloat = 0; sawByte = 0; }
  __syncthreads();
  const uint4 ld = ((const uint4*)am)[threadIdx.x];   // 256 threads * 16B = 4KB
  unsigned w[4] = {ld.x, ld.y, ld.z, ld.w};
  int f = 0, bm = 0;
  #pragma unroll
  for (int i = 0; i < 4; ++i){
    if (w[i] == 0x3F800000u) f = 1;
    else if (w[i] & ~1u)     bm = 1;
  }
  if (f)  atomicOr(&sawFloat, 1);
  if (bm) atomicOr(&sawByte, 1);
  __syncthreads();
  if (threadIdx.x == 0) *mode = sawFloat ? 2 : (sawByte ? 1 : 0);
}

// bias_pre[h][m][n] = rpb_table[rel_idx[n][m]*HEADS + h]
__global__ void bias_pre_kernel(const float* __restrict__ rpb, const int* __restrict__ rel_idx,
                                float* __restrict__ bias_pre){
  const int e = blockIdx.x*256 + threadIdx.x;
  if (e >= HEADS*NTOK*NTOK) return;
  const int rest = e & 4095, m = rest >> 6, n = rest & 63;
  bias_pre[e] = rpb[rel_idx[n*NTOK + m]*HEADS + (e >> 12)];
}

// convert the 4 weight matrices fp32 -> bf16 once (Wq,Wk,Wv,Wp contiguous in ws)
__global__ void wconv_kernel(const float* __restrict__ Wq, const float* __restrict__ Wk,
                             const float* __restrict__ Wv, const float* __restrict__ Wp,
                             unsigned short* __restrict__ wbf){
  const int e4 = blockIdx.x*256 + threadIdx.x;       // 4*36864/4 = 36864 float4s
  if (e4 >= 4*WMAT/4) return;
  const int mat = e4 / (WMAT/4);
  const int off = e4 - mat*(WMAT/4);
  const float* src = (mat==0)?Wq:(mat==1)?Wk:(mat==2)?Wv:Wp;
  const float4 f = ((const float4*)src)[off];
  unsigned short* dst = wbf + mat*WMAT + off*4;
  dst[0]=f2bf(f.x); dst[1]=f2bf(f.y); dst[2]=f2bf(f.z); dst[3]=f2bf(f.w);
}

// Fragment layout facts used (gfx950, m89-verified family):
//   mfma 16x16x32: A[row=l&15][k=8g+i], B[k=8g+i][col=l&15], C: col=l&15,row=4g+r
//   mfma 16x16x16: A[row=l&15][k=4g+r], B[k=4g+r][col=l&15], C: col=l&15,row=4g+r
// Chain: Q/K proj computed TRANSPOSED (A=W) -> C regs are exactly the
// 16x16x16 A/B frags of S^T = Kh*Qh^T; softmaxed S^T regs are directly the
// B-frag of out^T = Vh^T * P^T whose A-frag is the V-proj C regs.
// Phase structure (4 barriers): stage(q->xa, k->xb, madd) | B | QK-proj
// (+v prefetch to regs) | B | v->xa | B | V-proj, attn, xout->xb | B | P-proj.
__global__ __launch_bounds__(TPB, 3) void swin_kernel(
  const float* __restrict__ q, const float* __restrict__ kin, const float* __restrict__ vin,
  const float* __restrict__ mask, const void* __restrict__ amask,
  const unsigned short* __restrict__ wbf,
  const float* __restrict__ bq, const float* __restrict__ bk,
  const float* __restrict__ bv, const float* __restrict__ bp,
  const float* __restrict__ bias_pre, const int* __restrict__ mflag,
  float* __restrict__ out)
{
  __shared__ unsigned short xa[NTOK * XPITCH];   // 25.6 KB: q -> v -> (free)
  __shared__ unsigned short xb[NTOK * XPITCH];   // 25.6 KB: k -> xout
  __shared__ float madd[NTOK * MPITCH];          // 16.6 KB, [m][n]

  const int b    = blockIdx.x;
  const int t    = threadIdx.x;
  const int h    = t >> 6;          // wave == head
  const int lane = t & 63;
  const int l15  = lane & 15;
  const int g    = lane >> 4;
  const int c0   = h * HD;
  const size_t base = (size_t)b * (NTOK * DIM);
  const float scale = 0.17677669529663687f;   // 1/sqrt(32)
  const f32x4 fz = {0.f, 0.f, 0.f, 0.f};

  const unsigned short* Wq = wbf;
  const unsigned short* Wk = wbf + WMAT;
  const unsigned short* Wv = wbf + 2*WMAT;
  const unsigned short* Wp = wbf + 3*WMAT;

  // ---------- phase 0: madd + stage q->xa and k->xb (loads overlap) ----------
  {
    const int mode = mflag[0];
    const float* mrow = mask + (size_t)(b & (NWIN-1)) * (NTOK*NTOK);
    const size_t abase = (size_t)b * (NTOK*NTOK);
    for (int i = t; i < NTOK*NTOK; i += TPB){
      const int n = i >> 6, m = i & 63;
      bool msk;
      if (mode == 0)      msk = ((const int*)amask)[abase + i] != 0;
      else if (mode == 1) msk = ((const unsigned char*)amask)[abase + i] != 0;
      else                msk = ((const float*)amask)[abase + i] != 0.0f;
      madd[m*MPITCH + n] = mrow[i] + (msk ? -1e9f : 0.0f);
    }
    stage_xin(xa, q + base, t);
    stage_xin(xb, kin + base, t);
  }
  __syncthreads();

  bf16x4 Qf[4][2], Kf[4][2], Vf[2][4];

  // ---------- phase 1: v prefetch (regs) + Q-proj from xa + K-proj from xb ----------
  float4 vpre[8];
  #pragma unroll
  for (int j = 0; j < 8; ++j) vpre[j] = ((const float4*)(vin + base))[t + j*TPB];

  {  // Q projection (transposed): Qh^T[c][n]
    f32x4 acc[2][4];
    #pragma unroll
    for (int a0=0;a0<2;++a0){
      #pragma unroll
      for (int a1=0;a1<4;++a1) acc[a0][a1] = fz;
    }
    #pragma unroll
    for (int kt = 0; kt < 6; ++kt){
      const int k0 = kt*32 + g*8;
      const bf16x8 w0 = wfrag(Wq, c0 + l15, k0);
      const bf16x8 w1 = wfrag(Wq, c0 + 16 + l15, k0);
      #pragma unroll
      for (int nt = 0; nt < 4; ++nt){
        const bf16x8 xf = *(const bf16x8*)(xa + (nt*16 + l15)*XPITCH + k0);
        acc[0][nt] = mfma32(w0, xf, acc[0][nt]);
        acc[1][nt] = mfma32(w1, xf, acc[1][nt]);
      }
    }
    #pragma unroll
    for (int dt = 0; dt < 2; ++dt){
      const float4 bb = *(const float4*)(bq + c0 + dt*16 + g*4);
      #pragma unroll
      for (int nt = 0; nt < 4; ++nt){
        bf16x4 f;
        f[0]=(short)f2bf((acc[dt][nt][0]+bb.x)*scale);
        f[1]=(short)f2bf((acc[dt][nt][1]+bb.y)*scale);
        f[2]=(short)f2bf((acc[dt][nt][2]+bb.z)*scale);
        f[3]=(short)f2bf((acc[dt][nt][3]+bb.w)*scale);
        Qf[nt][dt] = f;
      }
    }
  }
  {  // K projection (transposed): Kh^T[c][m]
    f32x4 acc[2][4];
    #pragma unroll
    for (int a0=0;a0<2;++a0){
      #pragma unroll
      for (int a1=0;a1<4;++a1) acc[a0][a1] = fz;
    }
    #pragma unroll
    for (int kt = 0; kt < 6; ++kt){
      const int k0 = kt*32 + g*8;
      const bf16x8 w0 = wfrag(Wk, c0 + l15, k0);
      const bf16x8 w1 = wfrag(Wk, c0 + 16 + l15, k0);
      #pragma unroll
      for (int mt = 0; mt < 4; ++mt){
        const bf16x8 xf = *(const bf16x8*)(xb + (mt*16 + l15)*XPITCH + k0);
        acc[0][mt] = mfma32(w0, xf, acc[0][mt]);
        acc[1][mt] = mfma32(w1, xf, acc[1][mt]);
      }
    }
    #pragma unroll
    for (int dt = 0; dt < 2; ++dt){
      const float4 bb = *(const float4*)(bk + c0 + dt*16 + g*4);
      #pragma unroll
      for (int mt = 0; mt < 4; ++mt){
        bf16x4 f;
        f[0]=(short)f2bf(acc[dt][mt][0]+bb.x);
        f[1]=(short)f2bf(acc[dt][mt][1]+bb.y);
        f[2]=(short)f2bf(acc[dt][mt][2]+bb.z);
        f[3]=(short)f2bf(acc[dt][mt][3]+bb.w);
        Kf[mt][dt] = f;
      }
    }
  }
  __syncthreads();

  // ---------- phase 2: land v into xa ----------
  #pragma unroll
  for (int j = 0; j < 8; ++j){
    const int i4  = t + j*TPB;
    const int row = i4 / 48;
    const int col = (i4 - row*48) * 4;
    *(uint2*)(xa + row*XPITCH + col) = pack_bf(vpre[j]);
  }
  __syncthreads();

  // ---------- phase 3a: V projection (normal): Vh[m][c] ----------
  {
    f32x4 acc[4][2];
    #pragma unroll
    for (int a0=0;a0<4;++a0){
      #pragma unroll
      for (int a1=0;a1<2;++a1) acc[a0][a1] = fz;
    }
    #pragma unroll
    for (int kt = 0; kt < 6; ++kt){
      const int k0 = kt*32 + g*8;
      const bf16x8 w0 = wfrag(Wv, c0 + l15, k0);       // B-frag: Wv[c][k]
      const bf16x8 w1 = wfrag(Wv, c0 + 16 + l15, k0);
      #pragma unroll
      for (int mt = 0; mt < 4; ++mt){
        const bf16x8 xf = *(const bf16x8*)(xa + (mt*16 + l15)*XPITCH + k0);
        acc[mt][0] = mfma32(xf, w0, acc[mt][0]);
        acc[mt][1] = mfma32(xf, w1, acc[mt][1]);
      }
    }
    const float bv0 = bv[c0 + l15];
    const float bv1 = bv[c0 + 16 + l15];
    #pragma unroll
    for (int mt = 0; mt < 4; ++mt){
      bf16x4 f0, f1;
      f0[0]=(short)f2bf(acc[mt][0][0]+bv0); f0[1]=(short)f2bf(acc[mt][0][1]+bv0);
      f0[2]=(short)f2bf(acc[mt][0][2]+bv0); f0[3]=(short)f2bf(acc[mt][0][3]+bv0);
      f1[0]=(short)f2bf(acc[mt][1][0]+bv1); f1[1]=(short)f2bf(acc[mt][1][1]+bv1);
      f1[2]=(short)f2bf(acc[mt][1][2]+bv1); f1[3]=(short)f2bf(acc[mt][1][3]+bv1);
      Vf[0][mt] = f0;  // A[row=d=l15][k=m=4g+r]
      Vf[1][mt] = f1;
    }
  }

  // ---------- phase 3b: S^T = Kh * Qh^T ----------
  f32x4 s[4][4];
  #pragma unroll
  for (int mt = 0; mt < 4; ++mt){
    #pragma unroll
    for (int nt = 0; nt < 4; ++nt){
      f32x4 a = mfma16(Kf[mt][0], Qf[nt][0], fz);
      s[mt][nt] = mfma16(Kf[mt][1], Qf[nt][1], a);
    }
  }

  // ---------- phase 3c: bias/mask add + softmax over m ----------
  const float* bh = bias_pre + h * (NTOK*NTOK);
  bf16x4 Pf[4][4];
  #pragma unroll
  for (int nt = 0; nt < 4; ++nt){
    const int n = nt*16 + l15;
    float mx = -3.0e38f;
    #pragma unroll
    for (int mt = 0; mt < 4; ++mt){
      #pragma unroll
      for (int r = 0; r < 4; ++r){
        const int m = mt*16 + g*4 + r;
        const float val = s[mt][nt][r] + madd[m*MPITCH + n] + bh[m*64 + n];
        s[mt][nt][r] = val;
        mx = fmaxf(mx, val);
      }
    }
    mx = fmaxf(mx, __shfl_xor(mx, 16, 64));
    mx = fmaxf(mx, __shfl_xor(mx, 32, 64));
    float sum = 0.f;
    #pragma unroll
    for (int mt = 0; mt < 4; ++mt){
      #pragma unroll
      for (int r = 0; r < 4; ++r){
        const float e = __expf(s[mt][nt][r] - mx);
        s[mt][nt][r] = e;
        sum += e;
      }
    }
    sum += __shfl_xor(sum, 16, 64);
    sum += __shfl_xor(sum, 32, 64);
    const float inv = 1.0f / sum;
    #pragma unroll
    for (int ms = 0; ms < 4; ++ms){
      bf16x4 f;
      f[0]=(short)f2bf(s[ms][nt][0]*inv); f[1]=(short)f2bf(s[ms][nt][1]*inv);
      f[2]=(short)f2bf(s[ms][nt][2]*inv); f[3]=(short)f2bf(s[ms][nt][3]*inv);
      Pf[nt][ms] = f;   // B-frag: P^T[m][n]
    }
  }

  // ---------- phase 3d: out^T = Vh^T * P^T ----------
  f32x4 o[2][4];
  #pragma unroll
  for (int a0=0;a0<2;++a0){
    #pragma unroll
    for (int a1=0;a1<4;++a1) o[a0][a1] = fz;
  }
  #pragma unroll
  for (int ms = 0; ms < 4; ++ms){
    #pragma unroll
    for (int dt = 0; dt < 2; ++dt){
      #pragma unroll
      for (int nt = 0; nt < 4; ++nt){
        o[dt][nt] = mfma16(Vf[dt][ms], Pf[nt][ms], o[dt][nt]);
      }
    }
  }

  // ---------- phase 3e: write attention output into xb (k no longer needed) ----------
  #pragma unroll
  for (int dt = 0; dt < 2; ++dt){
    #pragma unroll
    for (int nt = 0; nt < 4; ++nt){
      const int n   = nt*16 + l15;
      const int col = c0 + dt*16 + g*4;
      uint2 u;
      u.x = (unsigned)f2bf(o[dt][nt][0]) | ((unsigned)f2bf(o[dt][nt][1]) << 16);
      u.y = (unsigned)f2bf(o[dt][nt][2]) | ((unsigned)f2bf(o[dt][nt][3]) << 16);
      *(uint2*)(xb + n*XPITCH + col) = u;
    }
  }
  __syncthreads();

  // ---------- phase 4: final projection out[n][c] = xout @ Wp^T + bp ----------
  {
    f32x4 acc[4][2];
    #pragma unroll
    for (int a0=0;a0<4;++a0){
      #pragma unroll
      for (int a1=0;a1<2;++a1) acc[a0][a1] = fz;
    }
    #pragma unroll
    for (int kt = 0; kt < 6; ++kt){
      const int k0 = kt*32 + g*8;
      const bf16x8 w0 = wfrag(Wp, c0 + l15, k0);
      const bf16x8 w1 = wfrag(Wp, c0 + 16 + l15, k0);
      #pragma unroll
      for (int nt = 0; nt < 4; ++nt){
        const bf16x8 xf = *(const bf16x8*)(xb + (nt*16 + l15)*XPITCH + k0);
        acc[nt][0] = mfma32(xf, w0, acc[nt][0]);
        acc[nt][1] = mfma32(xf, w1, acc[nt][1]);
      }
    }
    const float bp0 = bp[c0 + l15];
    const float bp1 = bp[c0 + 16 + l15];
    #pragma unroll
    for (int nt = 0; nt < 4; ++nt){
      #pragma unroll
      for (int ctl = 0; ctl < 2; ++ctl){
        const int c = c0 + ctl*16 + l15;
        const float badd = ctl ? bp1 : bp0;
        #pragma unroll
        for (int r = 0; r < 4; ++r){
          const int n = nt*16 + g*4 + r;
          out[base + (size_t)(n*DIM + c)] = acc[nt][ctl][r] + badd;
        }
      }
    }
  }
}

extern "C" void kernel_launch(void* const* d_in, const int* in_sizes, int n_in,
                              void* d_out, int out_size, void* d_ws, size_t ws_size,
                              hipStream_t stream){
  const float* q     = (const float*)d_in[0];
  const float* k     = (const float*)d_in[1];
  const float* v     = (const float*)d_in[2];
  const float* mask  = (const float*)d_in[3];
  const void*  amask = d_in[4];               // dtype resolved by device probe
  const float* Wq    = (const float*)d_in[5];
  const float* bq    = (const float*)d_in[6];
  const float* Wk    = (const float*)d_in[7];
  const float* bk    = (const float*)d_in[8];
  const float* Wv    = (const float*)d_in[9];
  const float* bv    = (const float*)d_in[10];
  const float* Wp    = (const float*)d_in[11];
  const float* bp    = (const float*)d_in[12];
  const float* rpb   = (const float*)d_in[13];
  const int*   ridx  = (const int*)d_in[14];
  float* out = (float*)d_out;

  // workspace layout: [0,98304) bias_pre | [98304,98308) mflag | [98560, +294912) wbf
  float*          bias_pre = (float*)d_ws;
  int*            mflag    = (int*)((char*)d_ws + 98304);
  unsigned short* wbf      = (unsigned short*)((char*)d_ws + 98560);

  detect_amask_kernel<<<1, 256, 0, stream>>>((const unsigned int*)amask, mflag);
  bias_pre_kernel<<<96, 256, 0, stream>>>(rpb, ridx, bias_pre);
  wconv_kernel<<<144, 256, 0, stream>>>(Wq, Wk, Wv, Wp, wbf);
  swin_kernel<<<NBLK, TPB, 0, stream>>>(q, k, v, mask, amask, wbf,
                                        bq, bk, bv, bp,
                                        bias_pre, mflag, out);
}